// Round 9
// baseline (45.355 us; speedup 1.0000x reference)
//
#include <hip/hip_runtime.h>

// RNN(tanh) fused forward — v6 "split-H": 2 lanes per chain.
// T=512, B=32768, H=2. 512 blocks x 192 threads (2 blocks/CU, 6 waves/CU).
// waves 0-1: split-H consumers. Lane pair (2j,2j+1) owns chain j; lane r
//   computes hidden row r only (half the fma+trans per lane), partner h
//   exchanged via DPP quad_perm (register file, no LDS). 1024 consumer
//   waves -> ~4/CU across all SIMDs (vs 2 in v5) and ~half the per-wave
//   critical path.
// wave 2: producer — global_load_lds(16B) double-buffered x staging only;
//   its vmcnt FIFO holds loads only, so the pre-barrier vmcnt(0) is pure
//   prefetch completion. Consumer stores are NT and never waited on.

#define T_STEPS 512
#define BATCH   32768
#define CH      32              // timesteps per chunk
#define NCH     (T_STEPS / CH)  // 16 chunks

typedef float v2f __attribute__((ext_vector_type(2)));

#define PROD_BARRIER() asm volatile("s_waitcnt vmcnt(0)\n\ts_barrier" ::: "memory")
#define CONS_BARRIER() asm volatile("s_waitcnt lgkmcnt(0)\n\ts_barrier" ::: "memory")

// lane<->lane^1 exchange via DPP quad_perm [1,0,3,2] (ctrl=0xB1)
__device__ __forceinline__ float dpp_xor1(float v) {
    return __builtin_bit_cast(float,
        __builtin_amdgcn_update_dpp(0, __builtin_bit_cast(int, v),
                                    0xB1, 0xF, 0xF, true));
}

__global__ __launch_bounds__(192) void rnn_sh_kernel(
    const v2f*   __restrict__ x,     // [T][B] float2
    const float* __restrict__ W_ih,  // [2][2]
    const float* __restrict__ W_hh,  // [2][2]
    const float* __restrict__ b_ih,  // [2]
    const float* __restrict__ b_hh,  // [2]
    const float* __restrict__ fc_w,  // [1][2]
    const float* __restrict__ fc_b,  // [1]
    float*       __restrict__ out)   // [T*B] output, then [B][2] h_last
{
    __shared__ v2f xbuf[2][CH][64];   // 32KB: x double buffer (64 chains)

    const int tid  = threadIdx.x;
    const int wave = tid >> 6;
    const int lane = tid & 63;
    const size_t bbase = (size_t)blockIdx.x * 64;

    const float L2E = 1.44269504088896340736f;   // log2(e)

    if (wave == 2) {
        // ---------------- producer: x prefetch only ----------------
        const int rofs = lane >> 5;           // which row of the 2-row pair
        const int cofs = (lane & 31) * 2;     // v2f offset within row

        #pragma unroll
        for (int k = 0; k < CH / 2; ++k) {
            const v2f* src = x + (size_t)(2 * k + rofs) * BATCH + bbase + cofs;
            __builtin_amdgcn_global_load_lds(
                (const __attribute__((address_space(1))) void*)src,
                (__attribute__((address_space(3))) void*)(&xbuf[0][2 * k][0] + lane * 2),
                16, 0, 0);
        }
        PROD_BARRIER();   // chunk 0 ready

        for (int c = 0; c < NCH; ++c) {
            if (c + 1 < NCH) {
                const size_t t0 = (size_t)(c + 1) * CH;
                #pragma unroll
                for (int k = 0; k < CH / 2; ++k) {
                    const v2f* src = x + (t0 + 2 * k + rofs) * BATCH + bbase + cofs;
                    __builtin_amdgcn_global_load_lds(
                        (const __attribute__((address_space(1))) void*)src,
                        (__attribute__((address_space(3))) void*)(&xbuf[(c + 1) & 1][2 * k][0] + lane * 2),
                        16, 0, 0);
                }
            }
            PROD_BARRIER();
        }
    } else {
        // -------- split-H consumers: lane pair (2j,2j+1) = chain j --------
        const int j = (wave << 5) + (lane >> 1);  // chain within block (0..63)
        const int r = lane & 1;                   // hidden row owned by lane

        const float S = 2.0f * L2E;  // pre-scale: a' = 2*log2e*a feeds exp2
        // row-r weights
        const float wr0 = W_ih[2 * r] * S,     wr1 = W_ih[2 * r + 1] * S;
        const float u_own  = W_hh[3 * r] * S;        // W_hh[r][r]
        const float u_part = W_hh[1 + r] * S;        // W_hh[0][1] or W_hh[1][0]
        const float bir = (b_ih[r] + b_hh[r]) * S;
        const float f_own  = fc_w[r] * L2E;
        const float f_part = fc_w[1 - r] * L2E;
        const float fb = fc_b[0] * L2E;

        float h_own = 0.0f, h_part = 0.0f;
        float* op = out + bbase + j;

        CONS_BARRIER();

        for (int c = 0; c < NCH; ++c) {
            // batch all x-reads of the chunk (pair lanes broadcast same addr)
            v2f xr[CH];
            #pragma unroll
            for (int i = 0; i < CH; ++i)
                xr[i] = xbuf[c & 1][i][j];

            const int tb = c * CH;
            #pragma unroll
            for (int i = 0; i < CH; ++i) {
                float a = fmaf(xr[i].x, wr0, fmaf(xr[i].y, wr1, bir));
                a = fmaf(h_own, u_own, a);
                a = fmaf(h_part, u_part, a);

                // tanh row r: h = 1 - 2/(exp2(a')+1)
                const float e = __builtin_amdgcn_exp2f(a);
                h_own = fmaf(-2.0f, __builtin_amdgcn_rcpf(e + 1.0f), 1.0f);

                // exchange with partner lane (register-file DPP)
                h_part = dpp_xor1(h_own);

                // fused projection + exp; even lane stores (NT, never waited)
                const float z = fmaf(h_own, f_own, fmaf(h_part, f_part, fb));
                const float zo = __builtin_amdgcn_exp2f(z);
                if (r == 0)
                    __builtin_nontemporal_store(zo, &op[(size_t)(tb + i) * BATCH]);
            }
            CONS_BARRIER();
        }

        // h_last: [1][B][2] — lane l writes (out+T*B)[2*bbase + 64*wave + l]
        __builtin_nontemporal_store(
            h_own, out + (size_t)T_STEPS * BATCH + 2 * bbase + (wave << 6) + lane);
    }
}

extern "C" void kernel_launch(void* const* d_in, const int* in_sizes, int n_in,
                              void* d_out, int out_size, void* d_ws, size_t ws_size,
                              hipStream_t stream) {
    const v2f*   x    = (const v2f*)d_in[0];
    const float* W_ih = (const float*)d_in[1];
    const float* W_hh = (const float*)d_in[2];
    const float* b_ih = (const float*)d_in[3];
    const float* b_hh = (const float*)d_in[4];
    const float* fc_w = (const float*)d_in[5];
    const float* fc_b = (const float*)d_in[6];
    float* out = (float*)d_out;

    rnn_sh_kernel<<<dim3(BATCH / 64), dim3(192), 0, stream>>>(
        x, W_ih, W_hh, b_ih, b_hh, fc_w, fc_b, out);
}

// Round 10
// 39.754 us; speedup vs baseline: 1.1409x; 1.1409x over previous
//
#include <hip/hip_runtime.h>

// RNN(tanh) fused forward — v7: counted-vmcnt deep-pipelined producer (T4).
// T=512, B=32768, H=2. 512 blocks x 128 threads (2 blocks/CU, 64KB LDS).
// wave1 = producer: 4-slot x ring, runs 2 chunks ahead; after issuing chunk
//   c+2's 16 global_load_lds it waits vmcnt(16) — chunk c+1 landed, chunk
//   c+2 still in flight ACROSS the barrier. Loads stay continuously
//   outstanding instead of burst+drain (the R5-R9 duty-cycle defect).
// wave0 = consumer: batched ds_reads -> regs, recurrence + exp2(f.h+b),
//   NT stores never waited on; lgkm-only barrier.

#define T_STEPS 512
#define BATCH   32768
#define CH      32              // timesteps per chunk
#define NCH     (T_STEPS / CH)  // 16 chunks
#define NSLOT   4               // ring slots (2 ready + 1 in flight + 1 read)

typedef float v2f __attribute__((ext_vector_type(2)));

#define BARRIER_VM16() asm volatile("s_waitcnt vmcnt(16)\n\ts_barrier" ::: "memory")
#define BARRIER_VM0()  asm volatile("s_waitcnt vmcnt(0)\n\ts_barrier" ::: "memory")
#define CONS_BARRIER() asm volatile("s_waitcnt lgkmcnt(0)\n\ts_barrier" ::: "memory")

__global__ __launch_bounds__(128) void rnn_pc7_kernel(
    const v2f*   __restrict__ x,     // [T][B] float2
    const float* __restrict__ W_ih,  // [2][2]
    const float* __restrict__ W_hh,  // [2][2]
    const float* __restrict__ b_ih,  // [2]
    const float* __restrict__ b_hh,  // [2]
    const float* __restrict__ fc_w,  // [1][2]
    const float* __restrict__ fc_b,  // [1]
    float*       __restrict__ out)   // [T*B] output, then [B][2] h_last
{
    __shared__ v2f xbuf[NSLOT][CH][64];   // 64KB x ring

    const int tid  = threadIdx.x;
    const int wave = tid >> 6;
    const int lane = tid & 63;
    const size_t bbase = (size_t)blockIdx.x * 64;

    const float L2E = 1.44269504088896340736f;   // log2(e)

    if (wave == 1) {
        // ---------------- producer: x prefetch only ----------------
        const int rofs = lane >> 5;           // which row of the 2-row pair
        const int cofs = (lane & 31) * 2;     // v2f offset within row

        // prologue: chunks 0 and 1 -> slots 0,1 (32 loads in flight)
        #pragma unroll
        for (int k = 0; k < CH; ++k) {        // 16 pairs over 2 chunks
            const int row = 2 * k;            // 0..30 of the 64-step window
            const v2f* src = x + (size_t)(row + rofs) * BATCH + bbase + cofs;
            __builtin_amdgcn_global_load_lds(
                (const __attribute__((address_space(1))) void*)src,
                (__attribute__((address_space(3))) void*)(&xbuf[0][0][0] + (size_t)row * 64 + lane * 2),
                16, 0, 0);
        }
        BARRIER_VM16();   // chunk 0 landed; chunk 1 still in flight

        for (int c = 0; c < NCH; ++c) {
            if (c + 2 < NCH) {
                const size_t t0 = (size_t)(c + 2) * CH;
                const int s = (c + 2) & (NSLOT - 1);
                #pragma unroll
                for (int k = 0; k < CH / 2; ++k) {
                    const v2f* src = x + (t0 + 2 * k + rofs) * BATCH + bbase + cofs;
                    __builtin_amdgcn_global_load_lds(
                        (const __attribute__((address_space(1))) void*)src,
                        (__attribute__((address_space(3))) void*)(&xbuf[s][2 * k][0] + lane * 2),
                        16, 0, 0);
                }
                BARRIER_VM16();   // chunk c+1 landed; c+2 in flight
            } else {
                BARRIER_VM0();    // tail: drain what's left
            }
        }
    } else {
        // ---------------- consumer: recurrence + direct output ----------------
        const float S = 2.0f * L2E;  // pre-scale: a' = 2*log2e*a feeds exp2
        const float w00 = W_ih[0]*S, w01 = W_ih[1]*S, w10 = W_ih[2]*S, w11 = W_ih[3]*S;
        const float u00 = W_hh[0]*S, u01 = W_hh[1]*S, u10 = W_hh[2]*S, u11 = W_hh[3]*S;
        const float bi0 = (b_ih[0] + b_hh[0])*S, bi1 = (b_ih[1] + b_hh[1])*S;
        const float f0 = fc_w[0]*L2E, f1 = fc_w[1]*L2E, fb = fc_b[0]*L2E;

        float h0 = 0.0f, h1 = 0.0f;
        float* op = out + bbase + lane;

        CONS_BARRIER();   // B0: chunk 0 ready

        for (int c = 0; c < NCH; ++c) {
            // phase 1: batch ALL x-reads of the chunk into registers
            v2f xr[CH];
            const int s = c & (NSLOT - 1);
            #pragma unroll
            for (int i = 0; i < CH; ++i)
                xr[i] = xbuf[s][i][lane];

            const int tb = c * CH;
            #pragma unroll
            for (int i = 0; i < CH; ++i) {
                float a0 = fmaf(xr[i].x, w00, fmaf(xr[i].y, w01, bi0));
                float a1 = fmaf(xr[i].x, w10, fmaf(xr[i].y, w11, bi1));
                a0 = fmaf(h1, u01, a0);  a0 = fmaf(h0, u00, a0);
                a1 = fmaf(h0, u10, a1);  a1 = fmaf(h1, u11, a1);

                // tanh(a) = 1 - 2/(exp2(a')+1)
                const float e0 = __builtin_amdgcn_exp2f(a0);
                const float e1 = __builtin_amdgcn_exp2f(a1);
                h0 = fmaf(-2.0f, __builtin_amdgcn_rcpf(e0 + 1.0f), 1.0f);
                h1 = fmaf(-2.0f, __builtin_amdgcn_rcpf(e1 + 1.0f), 1.0f);

                // fused projection + exp; store never waited on
                const float z = fmaf(h0, f0, fmaf(h1, f1, fb));
                __builtin_nontemporal_store(__builtin_amdgcn_exp2f(z),
                                            &op[(size_t)(tb + i) * BATCH]);
            }
            CONS_BARRIER();   // done reading slot s; wait for next chunk
        }

        // h_last: [1][B][2] — one 8B store per lane
        v2f hv; hv.x = h0; hv.y = h1;
        __builtin_nontemporal_store(hv, (v2f*)(out + (size_t)T_STEPS * BATCH) + bbase + lane);
    }
}

extern "C" void kernel_launch(void* const* d_in, const int* in_sizes, int n_in,
                              void* d_out, int out_size, void* d_ws, size_t ws_size,
                              hipStream_t stream) {
    const v2f*   x    = (const v2f*)d_in[0];
    const float* W_ih = (const float*)d_in[1];
    const float* W_hh = (const float*)d_in[2];
    const float* b_ih = (const float*)d_in[3];
    const float* b_hh = (const float*)d_in[4];
    const float* fc_w = (const float*)d_in[5];
    const float* fc_b = (const float*)d_in[6];
    float* out = (float*)d_out;

    rnn_pc7_kernel<<<dim3(BATCH / 64), dim3(128), 0, stream>>>(
        x, W_ih, W_hh, b_ih, b_hh, fc_w, fc_b, out);
}